// Round 9
// baseline (265.523 us; speedup 1.0000x reference)
//
#include <hip/hip_runtime.h>
#include <stdint.h>

// ---------------- problem constants ----------------
#define EMB   1024
#define NHEAD 16
#define CHD   64
#define NB    4
#define SEQ   2048
#define NTOK  (NB * SEQ)        // 8192
#define KDIM  1024

typedef __attribute__((ext_vector_type(8))) short  bf16x8;
typedef __attribute__((ext_vector_type(4))) short  short4v;
typedef __attribute__((ext_vector_type(4))) float  f32x4;
typedef __attribute__((ext_vector_type(4))) float  float4v;

// float -> bf16 (RNE), bit pattern in a short
__device__ __forceinline__ short f2bf(float f) {
    unsigned int u = __float_as_uint(f);
    u += 0x7fffu + ((u >> 16) & 1u);
    return (short)(u >> 16);
}

// async global->LDS, 16B per lane; lds base must be wave-uniform, lane i lands at base + i*16B
__device__ __forceinline__ void async16(const short* g, short* l) {
    __builtin_amdgcn_global_load_lds((__attribute__((address_space(1))) void const*)g,
                                     (__attribute__((address_space(3))) void*)l, 16, 0, 0);
}

// ---------------- fp32 -> bf16 convert, all 5 tensors in one launch ----------------
__global__ __launch_bounds__(256) void cvt_all(const float* __restrict__ x,
                                               const float* __restrict__ Wq,
                                               const float* __restrict__ Wk,
                                               const float* __restrict__ Wv,
                                               const float* __restrict__ Wo,
                                               short* __restrict__ xb,
                                               short* __restrict__ Wqb,
                                               short* __restrict__ Wkb,
                                               short* __restrict__ Wvb,
                                               short* __restrict__ Wob) {
    int bid = blockIdx.x;
    const float* src;
    short* dst;
    int idx;
    if (bid < 8192) {                       // x: 8192 blocks
        src = x; dst = xb; idx = bid * 256 + threadIdx.x;
    } else {                                // 4 weights: 1024 blocks each
        int w  = (bid - 8192) >> 10;
        int lb = (bid - 8192) & 1023;
        src = (w == 0) ? Wq : (w == 1) ? Wk : (w == 2) ? Wv : Wo;
        dst = (w == 0) ? Wqb : (w == 1) ? Wkb : (w == 2) ? Wvb : Wob;
        idx = lb * 256 + threadIdx.x;
    }
    float4v v = ((const float4v*)src)[idx];
    short4v s;
    s.x = f2bf(v.x); s.y = f2bf(v.y); s.z = f2bf(v.z); s.w = f2bf(v.w);
    ((short4v*)dst)[idx] = s;
}

// ---------------- shared GEMM core (128x128 tile, 1-phase; used by vproj/out_gemm) ----------------
__device__ __forceinline__ void gemm_core(const short* __restrict__ Atile,
                                          const short* __restrict__ Btile,
                                          short* As, short* Bs, f32x4 acc[4][4]) {
    const int tid  = threadIdx.x;
    const int wave = tid >> 6, lane = tid & 63;
    const int quad = lane >> 4, l16 = lane & 15;
    const int wm = (wave >> 1) * 64, wn = (wave & 1) * 64;
    const int srow = lane >> 2;
    const int scol = (lane & 3) * 8;

    for (int k0 = 0; k0 < KDIM; k0 += 32) {
        __syncthreads();
#pragma unroll
        for (int c = 0; c < 2; ++c) {
            int chunk = wave * 2 + c;
            int row = chunk * 16 + srow;
            async16(Atile + (size_t)row * KDIM + k0 + scol, As + chunk * 512);
            async16(Btile + (size_t)row * KDIM + k0 + scol, Bs + chunk * 512);
        }
        __syncthreads();
        bf16x8 af[4], bfr[4];
#pragma unroll
        for (int i = 0; i < 4; ++i)
            af[i] = *(const bf16x8*)&As[(wm + i * 16 + l16) * 32 + quad * 8];
#pragma unroll
        for (int j = 0; j < 4; ++j)
            bfr[j] = *(const bf16x8*)&Bs[(wn + j * 16 + l16) * 32 + quad * 8];
#pragma unroll
        for (int i = 0; i < 4; ++i)
#pragma unroll
            for (int j = 0; j < 4; ++j)
                acc[i][j] = __builtin_amdgcn_mfma_f32_16x16x32_bf16(af[i], bfr[j], acc[i][j], 0, 0, 0);
    }
}

#define QSCALE 0.1803368801111204f

// ================= Q/K projection: 256^2 tile, BK=64, 8-wave, 8-phase counted-vmcnt =================
// Template per learn_hip m201. Verified passing rounds 2-4, 7, 8. Grid (32,8) = 256 blocks =
// exactly 1 block/CU (128 KiB LDS) -- one full dispatch round.

#define MFMA16(A,B,C) __builtin_amdgcn_mfma_f32_16x16x32_bf16(A,B,C,0,0,0)
#define BARR  { __builtin_amdgcn_s_barrier(); __builtin_amdgcn_sched_barrier(0); }
#define VMC4  asm volatile("s_waitcnt vmcnt(4)" ::: "memory");
#define VMC8  asm volatile("s_waitcnt vmcnt(8)" ::: "memory");
#define VMC0  asm volatile("s_waitcnt vmcnt(0)" ::: "memory");
#define PRIO1 __builtin_amdgcn_s_setprio(1);
#define PRIO0 __builtin_amdgcn_s_setprio(0);

#define STAGE_A_(BUF,H,T) { \
    async16(aS0 + (size_t)(H)*131072 + (T)*64, sm + (BUF)*32768 + (H)*8192 + stA); \
    async16(aS1 + (size_t)(H)*131072 + (T)*64, sm + (BUF)*32768 + (H)*8192 + 4096 + stA); }
#define STAGE_B_(BUF,H,T) { \
    async16(bS0 + (size_t)(H)*131072 + (T)*64, sm + (BUF)*32768 + 16384 + (H)*8192 + stA); \
    async16(bS1 + (size_t)(H)*131072 + (T)*64, sm + (BUF)*32768 + 16384 + (H)*8192 + 4096 + stA); }

#define LDB_(BUF) { \
    const short* _pb = sm + (BUF)*32768 + bro; \
    bfr[0][0] = *(const bf16x8*)(_pb + ac0);        bfr[0][1] = *(const bf16x8*)(_pb + ac1); \
    bfr[1][0] = *(const bf16x8*)(_pb + 1024 + ac0); bfr[1][1] = *(const bf16x8*)(_pb + 1024 + ac1); \
    bfr[2][0] = *(const bf16x8*)(_pb + 2048 + ac0); bfr[2][1] = *(const bf16x8*)(_pb + 2048 + ac1); \
    bfr[3][0] = *(const bf16x8*)(_pb + 3072 + ac0); bfr[3][1] = *(const bf16x8*)(_pb + 3072 + ac1); }

#define LDA_(BUF,Q) { \
    const short* _pa = sm + (BUF)*32768 + aro + (Q)*2048; \
    af[0][0] = *(const bf16x8*)(_pa + ac0);        af[0][1] = *(const bf16x8*)(_pa + ac1); \
    af[1][0] = *(const bf16x8*)(_pa + 1024 + ac0); af[1][1] = *(const bf16x8*)(_pa + 1024 + ac1); }

#define MF_(Q) { \
    acc[2*(Q)][0]   = MFMA16(af[0][0], bfr[0][0], acc[2*(Q)][0]); \
    acc[2*(Q)][0]   = MFMA16(af[0][1], bfr[0][1], acc[2*(Q)][0]); \
    acc[2*(Q)][1]   = MFMA16(af[0][0], bfr[1][0], acc[2*(Q)][1]); \
    acc[2*(Q)][1]   = MFMA16(af[0][1], bfr[1][1], acc[2*(Q)][1]); \
    acc[2*(Q)][2]   = MFMA16(af[0][0], bfr[2][0], acc[2*(Q)][2]); \
    acc[2*(Q)][2]   = MFMA16(af[0][1], bfr[2][1], acc[2*(Q)][2]); \
    acc[2*(Q)][3]   = MFMA16(af[0][0], bfr[3][0], acc[2*(Q)][3]); \
    acc[2*(Q)][3]   = MFMA16(af[0][1], bfr[3][1], acc[2*(Q)][3]); \
    acc[2*(Q)+1][0] = MFMA16(af[1][0], bfr[0][0], acc[2*(Q)+1][0]); \
    acc[2*(Q)+1][0] = MFMA16(af[1][1], bfr[0][1], acc[2*(Q)+1][0]); \
    acc[2*(Q)+1][1] = MFMA16(af[1][0], bfr[1][0], acc[2*(Q)+1][1]); \
    acc[2*(Q)+1][1] = MFMA16(af[1][1], bfr[1][1], acc[2*(Q)+1][1]); \
    acc[2*(Q)+1][2] = MFMA16(af[1][0], bfr[2][0], acc[2*(Q)+1][2]); \
    acc[2*(Q)+1][2] = MFMA16(af[1][1], bfr[2][1], acc[2*(Q)+1][2]); \
    acc[2*(Q)+1][3] = MFMA16(af[1][0], bfr[3][0], acc[2*(Q)+1][3]); \
    acc[2*(Q)+1][3] = MFMA16(af[1][1], bfr[3][1], acc[2*(Q)+1][3]); }

#define WINDOW(RB, AB, TA, BB, TB) \
    LDB_(RB) LDA_(RB,0) STAGE_A_(AB,0,TA) BARR \
    PRIO1 MF_(0) PRIO0 BARR \
    LDA_(RB,1) STAGE_A_(AB,1,TA) BARR \
    PRIO1 MF_(1) PRIO0 BARR \
    LDA_(RB,2) STAGE_B_(BB,0,TB) BARR \
    PRIO1 MF_(2) PRIO0 BARR \
    LDA_(RB,3) STAGE_B_(BB,1,TB) BARR \
    PRIO1 MF_(3) PRIO0 VMC4 BARR

__global__ __launch_bounds__(512, 2) void qk256(const short* __restrict__ xb,
                                                const short* __restrict__ Wqk,
                                                const float* __restrict__ bq,
                                                const float* __restrict__ bk,
                                                short* __restrict__ Qb,
                                                short* __restrict__ Kb) {
    extern __shared__ short sm[];               // 65536 shorts = 128 KiB
    const int bm = blockIdx.x, bn = blockIdx.y;
    const int tid = threadIdx.x;
    const int w = tid >> 6, lane = tid & 63;
    const int kq = lane >> 4, l16 = lane & 15;
    const int wmi = w >> 2, wni = w & 3;        // 2M x 4N wave grid

    // staging: per-lane global source, pre-swizzled (inverse of read swizzle)
    const int colsw = ((lane & 7) * 8) ^ (((lane >> 5) & 1) << 4);
    const short* aS0 = xb  + (size_t)(bm * 256 + w * 8 + (lane >> 3)) * 1024 + colsw;
    const short* aS1 = aS0 + (size_t)64 * 1024;
    const short* bS0 = Wqk + (size_t)(bn * 256 + w * 8 + (lane >> 3)) * 1024 + colsw;
    const short* bS1 = bS0 + (size_t)64 * 1024;
    const int stA = w * 512;                    // wave-uniform LDS stage offset (shorts)

    // fragment-read offsets (swizzled)
    const int swz = (l16 & 4) ? 16 : 0;
    const int ac0 = (kq * 8) ^ swz;             // ks=0
    const int ac1 = (32 + kq * 8) ^ swz;        // ks=1
    const int aro = wmi * 8192 + l16 * 64;                                   // + m*1024
    const int bro = 16384 + (wni >> 1) * 8192 + ((wni & 1) * 64 + l16) * 64; // + n*1024

    f32x4 acc[8][4];
    const f32x4 z = {0.f, 0.f, 0.f, 0.f};
#pragma unroll
    for (int m = 0; m < 8; ++m)
#pragma unroll
        for (int n = 0; n < 4; ++n) acc[m][n] = z;
    bf16x8 bfr[4][2], af[2][2];

    // prologue: tile0 complete + tile1's B halves; drain tile0, keep tile1-B in flight
    STAGE_A_(0,0,0) STAGE_A_(0,1,0) STAGE_B_(0,0,0) STAGE_B_(0,1,0)
    STAGE_B_(1,0,1) STAGE_B_(1,1,1)
    VMC4 BARR

    for (int it = 0; it < 7; ++it) {
        const int te = 2 * it;
        WINDOW(0, 1, te + 1, 0, te + 2)
        WINDOW(1, 0, te + 2, 1, te + 3)
    }
    // tail: tiles 14 (buf0) / 15 (buf1), no stages past tile 15
    LDB_(0) LDA_(0,0) STAGE_A_(1,0,15) BARR
    PRIO1 MF_(0) PRIO0 BARR
    LDA_(0,1) STAGE_A_(1,1,15) BARR
    PRIO1 MF_(1) PRIO0 BARR
    LDA_(0,2) BARR
    PRIO1 MF_(2) PRIO0 BARR
    LDA_(0,3) BARR
    PRIO1 MF_(3) PRIO0 VMC0 BARR
    LDB_(1)
    LDA_(1,0) MF_(0)
    LDA_(1,1) MF_(1)
    LDA_(1,2) MF_(2)
    LDA_(1,3) MF_(3)

    // epilogue: rows = tokens (A side: kq*4+r), cols = features (B side: l16)
    const bool isQ = (bn < 4);
    const float* bias = isQ ? bq : bk;
    short* dst = isQ ? Qb : Kb;
    const float sc = isQ ? QSCALE : 1.0f;
    const int fb = (bn & 3) * 256 + wni * 64 + l16;   // feature within matrix, + n*16
    const int tok0 = bm * 256 + wmi * 128 + kq * 4;   // + m*16 + r
#pragma unroll
    for (int n = 0; n < 4; ++n) {
        const int e = fb + n * 16;
        const int hh = e >> 6, cc = e & 63;
        const float bv_ = bias[e];
#pragma unroll
        for (int m = 0; m < 8; ++m)
#pragma unroll
            for (int r = 0; r < 4; ++r) {
                const int tok = tok0 + m * 16 + r;
                const int bb = tok >> 11, nn = tok & 2047;
                dst[(((size_t)bb * NHEAD + hh) * SEQ + nn) * CHD + cc] =
                    f2bf((acc[m][n][r] + bv_) * sc);
            }
    }
}

// ---------------- V projection (swapped-operand 128^2 path: coalesced V^T store) ----------------
__global__ __launch_bounds__(256) void vproj(const short* __restrict__ xb,
                                             const short* __restrict__ Wvb,
                                             const float* __restrict__ bv,
                                             short* __restrict__ Vtb) {
    __shared__ short As[128 * 32], Bs[128 * 32];
    const int bm = blockIdx.x;
    const int ew = blockIdx.y * 128;

    f32x4 acc[4][4];
    const f32x4 z = {0.f, 0.f, 0.f, 0.f};
#pragma unroll
    for (int i = 0; i < 4; ++i)
#pragma unroll
        for (int j = 0; j < 4; ++j) acc[i][j] = z;

    // swapped: A = Wv rows (features), B = x rows (tokens)
    gemm_core(Wvb + (size_t)ew * KDIM, xb + (size_t)bm * 128 * KDIM, As, Bs, acc);

    const int lane = threadIdx.x & 63, wave = threadIdx.x >> 6;
    const int quad = lane >> 4, l16 = lane & 15;
    const int wm = (wave >> 1) * 64, wn = (wave & 1) * 64;
#pragma unroll
    for (int i = 0; i < 4; ++i)
#pragma unroll
        for (int j = 0; j < 4; ++j)
#pragma unroll
            for (int r = 0; r < 4; ++r) {
                int e = ew + wm + i * 16 + quad * 4 + r;
                int token = bm * 128 + wn + j * 16 + l16;
                int bb = token >> 11, nn = token & 2047;
                int hh = e >> 6, cc = e & 63;
                Vtb[(((size_t)bb * NHEAD + hh) * CHD + cc) * SEQ + nn] =
                    f2bf(acc[i][j][r] + bv[e]);
            }
}

// ---------------- flash attention (S^T formulation, P stays in registers) ----------------
// v7: G=2 geometry (R7-verified, 71.7us) + DOUBLE-BUFFERED K/V (64 KB LDS, 2 blocks/CU).
// R8 lesson: the per-kt vmcnt(0) drain was hidden by 16-wave TLP; halving TLP without
// removing the drain lost 10us. v7 removes the drain itself: stage tile t+2 into the
// buffer released by compute(t); before compute(t) wait only vmcnt(8) -- tile t's loads
// were issued a full iteration ago (~free), tile t+1's 8 stay in flight across the
// barrier (T3/T4: never vmcnt(0) in the main loop). Barrier count per tile unchanged (2),
// both now drain-free. Hazards: RAW = own vmcnt(8) + barrier => all waves' chunks landed;
// WAR = post-compute barrier precedes restaging; all frag ds_reads are consumed by MFMAs
// before that barrier, so their lgkmcnt waits retire pre-barrier.
__global__ __launch_bounds__(256, 2) void attn(const short* __restrict__ Qb,
                                               const short* __restrict__ Kb,
                                               const short* __restrict__ Vtb,
                                               short* __restrict__ AOb) {
    __shared__ short Ks[2][8192];       // [buf][128 kv x 64 ch] permuted rows, swizzled units
    __shared__ short Vs[2][8192];       // [buf][64 ch x 128 kv] swizzled units

    // XCD swizzle: lid%8 = XCD slot (round-robin dispatch); 8 bh per slot =>
    // per-XCD K+V working set 8 x 512 KB = 4 MB = one XCD L2.
    const int lid = blockIdx.x;                  // 0..1023
    const int bh = (lid & 7) * 8 + (lid >> 7);   // 0..63
    const int qt = (lid >> 3) & 15;              // 0..15 (128 q rows per block)

    const int tid = threadIdx.x, wave = tid >> 6, lane = tid & 63;
    const int quad = lane >> 4, l16 = lane & 15;

    const short* Kg = Kb  + (size_t)bh * SEQ * CHD;
    const short* Vg = Vtb + (size_t)bh * CHD * SEQ;

    // Q fragments straight from global (B-operand: n = q-row = l16, k = ch), two groups
    bf16x8 qf0[2], qf1[2];
#pragma unroll
    for (int g = 0; g < 2; ++g) {
        const short* Qg = Qb + ((size_t)bh * SEQ + qt * 128 + wave * 32 + g * 16 + l16) * CHD;
        qf0[g] = *(const bf16x8*)(Qg + quad * 8);
        qf1[g] = *(const bf16x8*)(Qg + 32 + quad * 8);
    }

    // staging lane geometry
    const int kr = lane >> 3, ku = (lane & 7) ^ kr;
    const int vr = lane >> 4, vu = (lane & 15) ^ (vr << 2);

    // precomputed staging offsets (lane-dependent, kt-invariant)
    int koff[4], voff[4];
#pragma unroll
    for (int cc = 0; cc < 4; ++cc) {
        int c = wave * 4 + cc;
        int l = c * 8 + kr;
        int j = l >> 4, m = l & 15;
        int kvg = ((j >> 1) << 5) + ((m >> 2) << 3) + ((j & 1) << 2) + (m & 3);
        koff[cc] = kvg * CHD + ku * 8;
        voff[cc] = (c * 4 + vr) * SEQ + vu * 8;
    }
    short* ksBase = &Ks[0][0];
    short* vsBase = &Vs[0][0];

    // frag-read LDS pointers (kt-invariant; +BUF*8192 selects buffer, compile-time)
    const int krow = l16 & 7;
    const int kbase = ((l16 >> 3) * 512) + krow * 64;
    const short* kp0 = ksBase + kbase + ((quad ^ krow) << 3);
    const short* kp1 = ksBase + kbase + (((4 + quad) ^ krow) << 3);
    const int vrow = l16 & 3;
    const short* vp = vsBase + (l16 >> 2) * 512 + vrow * 128 + quad * 8;

    const f32x4 zf = {0.f, 0.f, 0.f, 0.f};
    const bf16x8 onesv = {16256, 16256, 16256, 16256, 16256, 16256, 16256, 16256}; // bf16 1.0
    f32x4 O[2][4];
#pragma unroll
    for (int g = 0; g < 2; ++g)
#pragma unroll
        for (int nb = 0; nb < 4; ++nb) O[g][nb] = zf;
    f32x4 lacc[2];
    lacc[0] = zf; lacc[1] = zf;

#define ATTN_STAGE(BUF, T) { \
    const short* _kg = Kg + (size_t)(T) * (128 * CHD); \
    const short* _vg = Vg + (size_t)(T) * 128; \
    _Pragma("unroll") \
    for (int cc = 0; cc < 4; ++cc) { \
        async16(_kg + koff[cc], ksBase + (BUF) * 8192 + (wave * 4 + cc) * 512); \
        async16(_vg + voff[cc], vsBase + (BUF) * 8192 + (wave * 4 + cc) * 512); \
    } }

#define ATTN_COMPUTE(BUF) { \
    const short* kb0 = kp0 + (BUF) * 8192; \
    const short* kb1 = kp1 + (BUF) * 8192; \
    const short* vb  = vp  + (BUF) * 8192; \
    _Pragma("unroll") \
    for (int kk = 0; kk < 4; ++kk) { \
        bf16x8 kA0 = *(const bf16x8*)(kb0 + (2 * kk) * 1024); \
        bf16x8 kA1 = *(const bf16x8*)(kb1 + (2 * kk) * 1024); \
        bf16x8 kB0 = *(const bf16x8*)(kb0 + (2 * kk + 1) * 1024); \
        bf16x8 kB1 = *(const bf16x8*)(kb1 + (2 * kk + 1) * 1024); \
        union { int i[4]; bf16x8 v; } pf[2]; \
        _Pragma("unroll") \
        for (int g = 0; g < 2; ++g) { \
            PRIO1 \
            f32x4 sA = MFMA16(kA0, qf0[g], zf); \
            sA = MFMA16(kA1, qf1[g], sA); \
            f32x4 sB = MFMA16(kB0, qf0[g], zf); \
            sB = MFMA16(kB1, qf1[g], sB); \
            PRIO0 \
            unsigned a0 = __float_as_uint(__builtin_amdgcn_exp2f(sA.x)); \
            unsigned a1 = __float_as_uint(__builtin_amdgcn_exp2f(sA.y)); \
            unsigned a2 = __float_as_uint(__builtin_amdgcn_exp2f(sA.z)); \
            unsigned a3 = __float_as_uint(__builtin_amdgcn_exp2f(sA.w)); \
            unsigned b0 = __float_as_uint(__builtin_amdgcn_exp2f(sB.x)); \
            unsigned b1 = __float_as_uint(__builtin_amdgcn_exp2f(sB.y)); \
            unsigned b2 = __float_as_uint(__builtin_amdgcn_exp2f(sB.z)); \
            unsigned b3 = __float_as_uint(__builtin_amdgcn_exp2f(sB.w)); \
            pf[g].i[0] = __builtin_amdgcn_perm(a1, a0, 0x07060302u); \
            pf[g].i[1] = __builtin_amdgcn_perm(a3, a2, 0x07060302u); \
            pf[g].i[2] = __builtin_amdgcn_perm(b1, b0, 0x07060302u); \
            pf[g].i[3] = __builtin_amdgcn_perm(b3, b2, 0x07060302u); \
            lacc[g] = MFMA16(pf[g].v, onesv, lacc[g]); \
        } \
        const short* vpk = vb + ((kk ^ vrow) << 5); \
        PRIO1 \
        _Pragma("unroll") \
        for (int nb = 0; nb < 4; ++nb) { \
            bf16x8 vf = *(const bf16x8*)(vpk + nb * 2048); \
            _Pragma("unroll") \
            for (int g = 0; g < 2; ++g) \
                O[g][nb] = MFMA16(pf[g].v, vf, O[g][nb]); \
        } \
        PRIO0 \
    } }

    // prologue: tiles 0,1 in flight (16 loads/wave outstanding)
    ATTN_STAGE(0, 0)
    ATTN_STAGE(1, 1)

    for (int it = 0; it < 7; ++it) {
        VMC8 BARR                       // tile 2it landed everywhere (2it+1 in flight)
        ATTN_COMPUTE(0)                 // tile 2it
        BARR                            // all waves done reading buf0
        ATTN_STAGE(0, 2 * it + 2)       // flies during compute of tile 2it+1
        VMC8 BARR                       // tile 2it+1 landed (2it+2 in flight)
        ATTN_COMPUTE(1)                 // tile 2it+1
        BARR                            // all waves done reading buf1
        ATTN_STAGE(1, 2 * it + 3)       // flies during compute of tile 2it+2
    }
    // tail: tiles 14 (buf0), 15 (buf1); no further stages
    VMC8 BARR
    ATTN_COMPUTE(0)                     // tile 14
    VMC0 BARR                           // tile 15 fully landed
    ATTN_COMPUTE(1)                     // tile 15

#undef ATTN_STAGE
#undef ATTN_COMPUTE

    // epilogue: lacc[g][r] is the full row sum for q-row quad*4+r of group g
    const int b = bh >> 4, h = bh & 15;
#pragma unroll
    for (int g = 0; g < 2; ++g) {
        float linv[4];
#pragma unroll
        for (int r = 0; r < 4; ++r) linv[r] = 1.0f / lacc[g][r];
#pragma unroll
        for (int nb = 0; nb < 4; ++nb)
#pragma unroll
            for (int r = 0; r < 4; ++r) {
                int n = qt * 128 + wave * 32 + g * 16 + quad * 4 + r;
                int cc = nb * 16 + l16;
                AOb[((size_t)b * SEQ + n) * EMB + h * CHD + cc] = f2bf(O[g][nb][r] * linv[r]);
            }
    }
}

// ---------------- output projection ----------------
__global__ __launch_bounds__(256) void out_gemm(const short* __restrict__ AOb,
                                                const short* __restrict__ Wob,
                                                const float* __restrict__ bo,
                                                float* __restrict__ out) {
    __shared__ short As[128 * 32], Bs[128 * 32];
    const int bm = blockIdx.x, bn = blockIdx.y;

    f32x4 acc[4][4];
    const f32x4 z = {0.f, 0.f, 0.f, 0.f};
#pragma unroll
    for (int i = 0; i < 4; ++i)
#pragma unroll
        for (int j = 0; j < 4; ++j) acc[i][j] = z;

    gemm_core(AOb + (size_t)bm * 128 * KDIM, Wob + (size_t)bn * 128 * KDIM, As, Bs, acc);

    const int lane = threadIdx.x & 63, wave = threadIdx.x >> 6;
    const int quad = lane >> 4, l16 = lane & 15;
    const int wm = (wave >> 1) * 64, wn = (wave & 1) * 64;
#pragma unroll
    for (int i = 0; i < 4; ++i)
#pragma unroll
        for (int j = 0; j < 4; ++j)
#pragma unroll
            for (int r = 0; r < 4; ++r) {
                int token = bm * 128 + wm + i * 16 + quad * 4 + r;
                int e = bn * 128 + wn + j * 16 + l16;
                out[(size_t)token * EMB + e] = acc[i][j][r] + bo[e];
            }
}

// ---------------- launch ----------------
extern "C" void kernel_launch(void* const* d_in, const int* in_sizes, int n_in,
                              void* d_out, int out_size, void* d_ws, size_t ws_size,
                              hipStream_t stream) {
    const float* x  = (const float*)d_in[0];
    const float* Wq = (const float*)d_in[1];
    const float* bq = (const float*)d_in[2];
    const float* Wk = (const float*)d_in[3];
    const float* bk = (const float*)d_in[4];
    const float* Wv = (const float*)d_in[5];
    const float* bv = (const float*)d_in[6];
    const float* Wo = (const float*)d_in[7];
    const float* bo = (const float*)d_in[8];

    char* ws = (char*)d_ws;
    short* xb  = (short*)(ws + 0);                         // 16 MB
    short* Wqb = (short*)(ws + (size_t)16 * 1024 * 1024);  // 2 MB (Q rows 0-1023)
    short* Wkb = (short*)(ws + (size_t)18 * 1024 * 1024);  // 2 MB (K rows, contiguous after Q)
    short* Wvb = (short*)(ws + (size_t)20 * 1024 * 1024);
    short* Wob = (short*)(ws + (size_t)22 * 1024 * 1024);
    short* Qb  = (short*)(ws + (size_t)24 * 1024 * 1024);  // 16 MB
    short* Kb  = (short*)(ws + (size_t)40 * 1024 * 1024);  // 16 MB
    short* Vtb = (short*)(ws + (size_t)56 * 1024 * 1024);  // 16 MB
    short* AOb = (short*)(ws + (size_t)72 * 1024 * 1024);  // 16 MB

    static bool s_cfg = false;
    if (!s_cfg) {
        hipFuncSetAttribute(reinterpret_cast<const void*>(qk256),
                            hipFuncAttributeMaxDynamicSharedMemorySize, 131072);
        s_cfg = true;
    }

    cvt_all<<<dim3(8192 + 4096), dim3(256), 0, stream>>>(x, Wq, Wk, Wv, Wo,
                                                         xb, Wqb, Wkb, Wvb, Wob);
    qk256<<<dim3(32, 8), dim3(512), 131072, stream>>>(xb, Wqb, bq, bk, Qb, Kb);
    vproj<<<dim3(64, 8), dim3(256), 0, stream>>>(xb, Wvb, bv, Vtb);
    attn<<<dim3(1024), dim3(256), 0, stream>>>(Qb, Kb, Vtb, AOb);
    out_gemm<<<dim3(64, 8), dim3(256), 0, stream>>>(AOb, Wob, bo, (float*)d_out);
}

// Round 10
// 257.049 us; speedup vs baseline: 1.0330x; 1.0330x over previous
//
#include <hip/hip_runtime.h>
#include <stdint.h>

// ---------------- problem constants ----------------
#define EMB   1024
#define NHEAD 16
#define CHD   64
#define NB    4
#define SEQ   2048
#define NTOK  (NB * SEQ)        // 8192
#define KDIM  1024

typedef __attribute__((ext_vector_type(8))) short  bf16x8;
typedef __attribute__((ext_vector_type(4))) short  short4v;
typedef __attribute__((ext_vector_type(4))) float  f32x4;
typedef __attribute__((ext_vector_type(4))) float  float4v;

// float -> bf16 (RNE), bit pattern in a short
__device__ __forceinline__ short f2bf(float f) {
    unsigned int u = __float_as_uint(f);
    u += 0x7fffu + ((u >> 16) & 1u);
    return (short)(u >> 16);
}

// async global->LDS, 16B per lane; lds base must be wave-uniform, lane i lands at base + i*16B
__device__ __forceinline__ void async16(const short* g, short* l) {
    __builtin_amdgcn_global_load_lds((__attribute__((address_space(1))) void const*)g,
                                     (__attribute__((address_space(3))) void*)l, 16, 0, 0);
}

#define MFMA16(A,B,C) __builtin_amdgcn_mfma_f32_16x16x32_bf16(A,B,C,0,0,0)
#define BARR  { __builtin_amdgcn_s_barrier(); __builtin_amdgcn_sched_barrier(0); }
#define VMC4  asm volatile("s_waitcnt vmcnt(4)" ::: "memory");
#define VMC0  asm volatile("s_waitcnt vmcnt(0)" ::: "memory");
#define PRIO1 __builtin_amdgcn_s_setprio(1);
#define PRIO0 __builtin_amdgcn_s_setprio(0);

// ---------------- fp32 -> bf16 convert, all 5 tensors in one launch ----------------
__global__ __launch_bounds__(256) void cvt_all(const float* __restrict__ x,
                                               const float* __restrict__ Wq,
                                               const float* __restrict__ Wk,
                                               const float* __restrict__ Wv,
                                               const float* __restrict__ Wo,
                                               short* __restrict__ xb,
                                               short* __restrict__ Wqb,
                                               short* __restrict__ Wkb,
                                               short* __restrict__ Wvb,
                                               short* __restrict__ Wob) {
    int bid = blockIdx.x;
    const float* src;
    short* dst;
    int idx;
    if (bid < 8192) {                       // x: 8192 blocks
        src = x; dst = xb; idx = bid * 256 + threadIdx.x;
    } else {                                // 4 weights: 1024 blocks each
        int w  = (bid - 8192) >> 10;
        int lb = (bid - 8192) & 1023;
        src = (w == 0) ? Wq : (w == 1) ? Wk : (w == 2) ? Wv : Wo;
        dst = (w == 0) ? Wqb : (w == 1) ? Wkb : (w == 2) ? Wvb : Wob;
        idx = lb * 256 + threadIdx.x;
    }
    float4v v = ((const float4v*)src)[idx];
    short4v s;
    s.x = f2bf(v.x); s.y = f2bf(v.y); s.z = f2bf(v.z); s.w = f2bf(v.w);
    ((short4v*)dst)[idx] = s;
}

// ---------------- shared GEMM core: 128x128 tile, 2-PHASE double-buffered ----------------
// T3 "minimum 2-phase" (catalog m248): STAGE(t+1) issued BEFORE compute(t); the vmcnt(0)
// at the next step's head then waits on loads that had a full compute phase (~300cyc) to
// fly -- the 1-phase version's exposed drain is gone. Barriers per K-step unchanged (2):
// BARR_A (tile t visible everywhere) and BARR_B (all waves done reading buf -> safe to
// restage next step). LDS 2x16KB = 32KB -> still >=4 blocks/CU at 256 threads (R8/R9
// lesson: never trade occupancy for drain removal).
#define GSTAGE(b, t) { \
    _Pragma("unroll") \
    for (int c = 0; c < 2; ++c) { \
        int chunk = wave * 2 + c; \
        int row = chunk * 16 + srow; \
        async16(Atile + (size_t)row * KDIM + (t) * 32 + scol, As + (b) * 4096 + chunk * 512); \
        async16(Btile + (size_t)row * KDIM + (t) * 32 + scol, Bs + (b) * 4096 + chunk * 512); \
    } }

#define GCOMPUTE(b) { \
    bf16x8 af[4], bfr[4]; \
    _Pragma("unroll") \
    for (int i = 0; i < 4; ++i) \
        af[i] = *(const bf16x8*)&As[(b) * 4096 + (wm + i * 16 + l16) * 32 + quad * 8]; \
    _Pragma("unroll") \
    for (int j = 0; j < 4; ++j) \
        bfr[j] = *(const bf16x8*)&Bs[(b) * 4096 + (wn + j * 16 + l16) * 32 + quad * 8]; \
    PRIO1 \
    _Pragma("unroll") \
    for (int i = 0; i < 4; ++i) \
        _Pragma("unroll") \
        for (int j = 0; j < 4; ++j) \
            acc[i][j] = MFMA16(af[i], bfr[j], acc[i][j]); \
    PRIO0 }

__device__ __forceinline__ void gemm_core(const short* __restrict__ Atile,
                                          const short* __restrict__ Btile,
                                          short* As, short* Bs, f32x4 acc[4][4]) {
    const int tid  = threadIdx.x;
    const int wave = tid >> 6, lane = tid & 63;
    const int quad = lane >> 4, l16 = lane & 15;
    const int wm = (wave >> 1) * 64, wn = (wave & 1) * 64;
    const int srow = lane >> 2;
    const int scol = (lane & 3) * 8;

    GSTAGE(0, 0)
    for (int t = 0; t < 32; t += 2) {
        VMC0 BARR                      // tile t landed everywhere (BARR_A)
        GSTAGE(1, t + 1)               // flies during compute(t); buf1 safe (BARR_B of t-1)
        GCOMPUTE(0)
        BARR                           // BARR_B: all waves done reading buf0
        VMC0 BARR                      // tile t+1 landed everywhere
        if (t + 2 < 32) GSTAGE(0, t + 2)
        GCOMPUTE(1)
        BARR
    }
}

#define QSCALE 0.1803368801111204f

// ================= Q/K projection: 256^2 tile, BK=64, 8-wave, 8-phase counted-vmcnt =================
// Template per learn_hip m201. Verified passing rounds 2-4, 7-9. Grid (32,8) = 256 blocks =
// exactly 1 block/CU (128 KiB LDS) -- one full dispatch round.

#define STAGE_A_(BUF,H,T) { \
    async16(aS0 + (size_t)(H)*131072 + (T)*64, sm + (BUF)*32768 + (H)*8192 + stA); \
    async16(aS1 + (size_t)(H)*131072 + (T)*64, sm + (BUF)*32768 + (H)*8192 + 4096 + stA); }
#define STAGE_B_(BUF,H,T) { \
    async16(bS0 + (size_t)(H)*131072 + (T)*64, sm + (BUF)*32768 + 16384 + (H)*8192 + stA); \
    async16(bS1 + (size_t)(H)*131072 + (T)*64, sm + (BUF)*32768 + 16384 + (H)*8192 + 4096 + stA); }

#define LDB_(BUF) { \
    const short* _pb = sm + (BUF)*32768 + bro; \
    bfr[0][0] = *(const bf16x8*)(_pb + ac0);        bfr[0][1] = *(const bf16x8*)(_pb + ac1); \
    bfr[1][0] = *(const bf16x8*)(_pb + 1024 + ac0); bfr[1][1] = *(const bf16x8*)(_pb + 1024 + ac1); \
    bfr[2][0] = *(const bf16x8*)(_pb + 2048 + ac0); bfr[2][1] = *(const bf16x8*)(_pb + 2048 + ac1); \
    bfr[3][0] = *(const bf16x8*)(_pb + 3072 + ac0); bfr[3][1] = *(const bf16x8*)(_pb + 3072 + ac1); }

#define LDA_(BUF,Q) { \
    const short* _pa = sm + (BUF)*32768 + aro + (Q)*2048; \
    af[0][0] = *(const bf16x8*)(_pa + ac0);        af[0][1] = *(const bf16x8*)(_pa + ac1); \
    af[1][0] = *(const bf16x8*)(_pa + 1024 + ac0); af[1][1] = *(const bf16x8*)(_pa + 1024 + ac1); }

#define MF_(Q) { \
    acc[2*(Q)][0]   = MFMA16(af[0][0], bfr[0][0], acc[2*(Q)][0]); \
    acc[2*(Q)][0]   = MFMA16(af[0][1], bfr[0][1], acc[2*(Q)][0]); \
    acc[2*(Q)][1]   = MFMA16(af[0][0], bfr[1][0], acc[2*(Q)][1]); \
    acc[2*(Q)][1]   = MFMA16(af[0][1], bfr[1][1], acc[2*(Q)][1]); \
    acc[2*(Q)][2]   = MFMA16(af[0][0], bfr[2][0], acc[2*(Q)][2]); \
    acc[2*(Q)][2]   = MFMA16(af[0][1], bfr[2][1], acc[2*(Q)][2]); \
    acc[2*(Q)][3]   = MFMA16(af[0][0], bfr[3][0], acc[2*(Q)][3]); \
    acc[2*(Q)][3]   = MFMA16(af[0][1], bfr[3][1], acc[2*(Q)][3]); \
    acc[2*(Q)+1][0] = MFMA16(af[1][0], bfr[0][0], acc[2*(Q)+1][0]); \
    acc[2*(Q)+1][0] = MFMA16(af[1][1], bfr[0][1], acc[2*(Q)+1][0]); \
    acc[2*(Q)+1][1] = MFMA16(af[1][0], bfr[1][0], acc[2*(Q)+1][1]); \
    acc[2*(Q)+1][1] = MFMA16(af[1][1], bfr[1][1], acc[2*(Q)+1][1]); \
    acc[2*(Q)+1][2] = MFMA16(af[1][0], bfr[2][0], acc[2*(Q)+1][2]); \
    acc[2*(Q)+1][2] = MFMA16(af[1][1], bfr[2][1], acc[2*(Q)+1][2]); \
    acc[2*(Q)+1][3] = MFMA16(af[1][0], bfr[3][0], acc[2*(Q)+1][3]); \
    acc[2*(Q)+1][3] = MFMA16(af[1][1], bfr[3][1], acc[2*(Q)+1][3]); }

#define WINDOW(RB, AB, TA, BB, TB) \
    LDB_(RB) LDA_(RB,0) STAGE_A_(AB,0,TA) BARR \
    PRIO1 MF_(0) PRIO0 BARR \
    LDA_(RB,1) STAGE_A_(AB,1,TA) BARR \
    PRIO1 MF_(1) PRIO0 BARR \
    LDA_(RB,2) STAGE_B_(BB,0,TB) BARR \
    PRIO1 MF_(2) PRIO0 BARR \
    LDA_(RB,3) STAGE_B_(BB,1,TB) BARR \
    PRIO1 MF_(3) PRIO0 VMC4 BARR

__global__ __launch_bounds__(512, 2) void qk256(const short* __restrict__ xb,
                                                const short* __restrict__ Wqk,
                                                const float* __restrict__ bq,
                                                const float* __restrict__ bk,
                                                short* __restrict__ Qb,
                                                short* __restrict__ Kb) {
    extern __shared__ short sm[];               // 65536 shorts = 128 KiB
    const int bm = blockIdx.x, bn = blockIdx.y;
    const int tid = threadIdx.x;
    const int w = tid >> 6, lane = tid & 63;
    const int kq = lane >> 4, l16 = lane & 15;
    const int wmi = w >> 2, wni = w & 3;        // 2M x 4N wave grid

    // staging: per-lane global source, pre-swizzled (inverse of read swizzle)
    const int colsw = ((lane & 7) * 8) ^ (((lane >> 5) & 1) << 4);
    const short* aS0 = xb  + (size_t)(bm * 256 + w * 8 + (lane >> 3)) * 1024 + colsw;
    const short* aS1 = aS0 + (size_t)64 * 1024;
    const short* bS0 = Wqk + (size_t)(bn * 256 + w * 8 + (lane >> 3)) * 1024 + colsw;
    const short* bS1 = bS0 + (size_t)64 * 1024;
    const int stA = w * 512;                    // wave-uniform LDS stage offset (shorts)

    // fragment-read offsets (swizzled)
    const int swz = (l16 & 4) ? 16 : 0;
    const int ac0 = (kq * 8) ^ swz;             // ks=0
    const int ac1 = (32 + kq * 8) ^ swz;        // ks=1
    const int aro = wmi * 8192 + l16 * 64;                                   // + m*1024
    const int bro = 16384 + (wni >> 1) * 8192 + ((wni & 1) * 64 + l16) * 64; // + n*1024

    f32x4 acc[8][4];
    const f32x4 z = {0.f, 0.f, 0.f, 0.f};
#pragma unroll
    for (int m = 0; m < 8; ++m)
#pragma unroll
        for (int n = 0; n < 4; ++n) acc[m][n] = z;
    bf16x8 bfr[4][2], af[2][2];

    // prologue: tile0 complete + tile1's B halves; drain tile0, keep tile1-B in flight
    STAGE_A_(0,0,0) STAGE_A_(0,1,0) STAGE_B_(0,0,0) STAGE_B_(0,1,0)
    STAGE_B_(1,0,1) STAGE_B_(1,1,1)
    VMC4 BARR

    for (int it = 0; it < 7; ++it) {
        const int te = 2 * it;
        WINDOW(0, 1, te + 1, 0, te + 2)
        WINDOW(1, 0, te + 2, 1, te + 3)
    }
    // tail: tiles 14 (buf0) / 15 (buf1), no stages past tile 15
    LDB_(0) LDA_(0,0) STAGE_A_(1,0,15) BARR
    PRIO1 MF_(0) PRIO0 BARR
    LDA_(0,1) STAGE_A_(1,1,15) BARR
    PRIO1 MF_(1) PRIO0 BARR
    LDA_(0,2) BARR
    PRIO1 MF_(2) PRIO0 BARR
    LDA_(0,3) BARR
    PRIO1 MF_(3) PRIO0 VMC0 BARR
    LDB_(1)
    LDA_(1,0) MF_(0)
    LDA_(1,1) MF_(1)
    LDA_(1,2) MF_(2)
    LDA_(1,3) MF_(3)

    // epilogue: rows = tokens (A side: kq*4+r), cols = features (B side: l16)
    const bool isQ = (bn < 4);
    const float* bias = isQ ? bq : bk;
    short* dst = isQ ? Qb : Kb;
    const float sc = isQ ? QSCALE : 1.0f;
    const int fb = (bn & 3) * 256 + wni * 64 + l16;   // feature within matrix, + n*16
    const int tok0 = bm * 256 + wmi * 128 + kq * 4;   // + m*16 + r
#pragma unroll
    for (int n = 0; n < 4; ++n) {
        const int e = fb + n * 16;
        const int hh = e >> 6, cc = e & 63;
        const float bv_ = bias[e];
#pragma unroll
        for (int m = 0; m < 8; ++m)
#pragma unroll
            for (int r = 0; r < 4; ++r) {
                const int tok = tok0 + m * 16 + r;
                const int bb = tok >> 11, nn = tok & 2047;
                dst[(((size_t)bb * NHEAD + hh) * SEQ + nn) * CHD + cc] =
                    f2bf((acc[m][n][r] + bv_) * sc);
            }
    }
}

// ---------------- V projection (swapped-operand 128^2 path: coalesced V^T store) ----------------
__global__ __launch_bounds__(256) void vproj(const short* __restrict__ xb,
                                             const short* __restrict__ Wvb,
                                             const float* __restrict__ bv,
                                             short* __restrict__ Vtb) {
    __shared__ short As[2 * 4096], Bs[2 * 4096];
    const int bm = blockIdx.x;
    const int ew = blockIdx.y * 128;

    f32x4 acc[4][4];
    const f32x4 z = {0.f, 0.f, 0.f, 0.f};
#pragma unroll
    for (int i = 0; i < 4; ++i)
#pragma unroll
        for (int j = 0; j < 4; ++j) acc[i][j] = z;

    // swapped: A = Wv rows (features), B = x rows (tokens)
    gemm_core(Wvb + (size_t)ew * KDIM, xb + (size_t)bm * 128 * KDIM, As, Bs, acc);

    const int lane = threadIdx.x & 63, wave = threadIdx.x >> 6;
    const int quad = lane >> 4, l16 = lane & 15;
    const int wm = (wave >> 1) * 64, wn = (wave & 1) * 64;
#pragma unroll
    for (int i = 0; i < 4; ++i)
#pragma unroll
        for (int j = 0; j < 4; ++j)
#pragma unroll
            for (int r = 0; r < 4; ++r) {
                int e = ew + wm + i * 16 + quad * 4 + r;
                int token = bm * 128 + wn + j * 16 + l16;
                int bb = token >> 11, nn = token & 2047;
                int hh = e >> 6, cc = e & 63;
                Vtb[(((size_t)bb * NHEAD + hh) * CHD + cc) * SEQ + nn] =
                    f2bf(acc[i][j][r] + bv[e]);
            }
}

// ---------------- flash attention (S^T formulation, P stays in registers) ----------------
// R7-EXACT (verified 71.7us): G=2, single-buffer 32KB LDS, 4 blocks/CU, fused 2-syncthreads
// structure, XCD swizzle, setprio. R8 (G=4, 2 blocks/CU: 81.9) and R9 (dbuf 64KB,
// 2 blocks/CU: 83.9) both proved: at 4 blocks/CU the 16-wave TLP already hides the staging
// drain; trading occupancy for drain removal loses ~12us. This structure is issue-saturated
// (MfmaUtil 47 + VALUBusy 44 = 91%) -- the local optimum for this formulation.
__global__ __launch_bounds__(256, 4) void attn(const short* __restrict__ Qb,
                                               const short* __restrict__ Kb,
                                               const short* __restrict__ Vtb,
                                               short* __restrict__ AOb) {
    __shared__ short Ks[16 * 512];      // 128 kv x 64 ch (permuted rows, swizzled units)
    __shared__ short Vs[16 * 512];      // 64 ch x 128 kv (swizzled units)

    // XCD swizzle: lid%8 = XCD slot (round-robin dispatch); 8 bh per slot =>
    // per-XCD K+V working set 8 x 512 KB = 4 MB = one XCD L2.
    const int lid = blockIdx.x;                  // 0..1023
    const int bh = (lid & 7) * 8 + (lid >> 7);   // 0..63
    const int qt = (lid >> 3) & 15;              // 0..15

    const int tid = threadIdx.x, wave = tid >> 6, lane = tid & 63;
    const int quad = lane >> 4, l16 = lane & 15;

    const short* Kg = Kb  + (size_t)bh * SEQ * CHD;
    const short* Vg = Vtb + (size_t)bh * CHD * SEQ;

    // Q fragments straight from global (B-operand: n = q-row = l16, k = ch), two groups
    bf16x8 qf0[2], qf1[2];
#pragma unroll
    for (int g = 0; g < 2; ++g) {
        const short* Qg = Qb + ((size_t)bh * SEQ + qt * 128 + wave * 32 + g * 16 + l16) * CHD;
        qf0[g] = *(const bf16x8*)(Qg + quad * 8);
        qf1[g] = *(const bf16x8*)(Qg + 32 + quad * 8);
    }

    // staging lane geometry
    const int kr = lane >> 3, ku = (lane & 7) ^ kr;
    const int vr = lane >> 4, vu = (lane & 15) ^ (vr << 2);

    // precomputed staging offsets (lane-dependent, kt-invariant)
    int koff[4], voff[4];
#pragma unroll
    for (int cc = 0; cc < 4; ++cc) {
        int c = wave * 4 + cc;
        int l = c * 8 + kr;
        int j = l >> 4, m = l & 15;
        int kvg = ((j >> 1) << 5) + ((m >> 2) << 3) + ((j & 1) << 2) + (m & 3);
        koff[cc] = kvg * CHD + ku * 8;
        voff[cc] = (c * 4 + vr) * SEQ + vu * 8;
    }

    // frag-read LDS pointers (kt-invariant, immediate offsets inside the loop)
    const int krow = l16 & 7;
    const int kbase = ((l16 >> 3) * 512) + krow * 64;
    const short* kp0 = Ks + kbase + ((quad ^ krow) << 3);
    const short* kp1 = Ks + kbase + (((4 + quad) ^ krow) << 3);
    const int vrow = l16 & 3;
    const short* vp = Vs + (l16 >> 2) * 512 + vrow * 128 + quad * 8;

    const f32x4 zf = {0.f, 0.f, 0.f, 0.f};
    const bf16x8 onesv = {16256, 16256, 16256, 16256, 16256, 16256, 16256, 16256}; // bf16 1.0
    f32x4 O[2][4];
#pragma unroll
    for (int g = 0; g < 2; ++g)
#pragma unroll
        for (int nb = 0; nb < 4; ++nb) O[g][nb] = zf;
    f32x4 lacc[2];
    lacc[0] = zf; lacc[1] = zf;

    const short* Kgp = Kg;
    const short* Vgp = Vg;

    for (int kt = 0; kt < 16; ++kt) {
        __syncthreads();   // previous iteration's frag reads done
#pragma unroll
        for (int cc = 0; cc < 4; ++cc) {
            int c = wave * 4 + cc;
            async16(Kgp + koff[cc], Ks + c * 512);
            async16(Vgp + voff[cc], Vs + c * 512);
        }
        Kgp += 128 * CHD;
        Vgp += 128;
        __syncthreads();   // staging drained

        // fused per-kk: S^T (pair j=2kk,2kk+1), exp2, row-sum MFMA, PV MFMAs.
        // K/V frags read ONCE, used by both q-groups.
#pragma unroll
        for (int kk = 0; kk < 4; ++kk) {
            bf16x8 kA0 = *(const bf16x8*)(kp0 + (2 * kk) * 1024);
            bf16x8 kA1 = *(const bf16x8*)(kp1 + (2 * kk) * 1024);
            bf16x8 kB0 = *(const bf16x8*)(kp0 + (2 * kk + 1) * 1024);
            bf16x8 kB1 = *(const bf16x8*)(kp1 + (2 * kk + 1) * 1024);

            union { int i[4]; bf16x8 v; } pf[2];
#pragma unroll
            for (int g = 0; g < 2; ++g) {
                PRIO1
                f32x4 sA = __builtin_amdgcn_mfma_f32_16x16x32_bf16(kA0, qf0[g], zf, 0, 0, 0);
                sA = __builtin_amdgcn_mfma_f32_16x16x32_bf16(kA1, qf1[g], sA, 0, 0, 0);
                f32x4 sB = __builtin_amdgcn_mfma_f32_16x16x32_bf16(kB0, qf0[g], zf, 0, 0, 0);
                sB = __builtin_amdgcn_mfma_f32_16x16x32_bf16(kB1, qf1[g], sB, 0, 0, 0);
                PRIO0

                unsigned a0 = __float_as_uint(__builtin_amdgcn_exp2f(sA.x));
                unsigned a1 = __float_as_uint(__builtin_amdgcn_exp2f(sA.y));
                unsigned a2 = __float_as_uint(__builtin_amdgcn_exp2f(sA.z));
                unsigned a3 = __float_as_uint(__builtin_amdgcn_exp2f(sA.w));
                unsigned b0 = __float_as_uint(__builtin_amdgcn_exp2f(sB.x));
                unsigned b1 = __float_as_uint(__builtin_amdgcn_exp2f(sB.y));
                unsigned b2 = __float_as_uint(__builtin_amdgcn_exp2f(sB.z));
                unsigned b3 = __float_as_uint(__builtin_amdgcn_exp2f(sB.w));
                pf[g].i[0] = __builtin_amdgcn_perm(a1, a0, 0x07060302u);
                pf[g].i[1] = __builtin_amdgcn_perm(a3, a2, 0x07060302u);
                pf[g].i[2] = __builtin_amdgcn_perm(b1, b0, 0x07060302u);
                pf[g].i[3] = __builtin_amdgcn_perm(b3, b2, 0x07060302u);

                lacc[g] = __builtin_amdgcn_mfma_f32_16x16x32_bf16(pf[g].v, onesv, lacc[g], 0, 0, 0);
            }

            const short* vpk = vp + ((kk ^ vrow) << 5);
            PRIO1
#pragma unroll
            for (int nb = 0; nb < 4; ++nb) {
                bf16x8 vf = *(const bf16x8*)(vpk + nb * 2048);
#pragma unroll
                for (int g = 0; g < 2; ++g)
                    O[g][nb] = __builtin_amdgcn_mfma_f32_16x16x32_bf16(pf[g].v, vf, O[g][nb], 0, 0, 0);
            }
            PRIO0
        }
    }

    // epilogue: lacc[g][r] is the full row sum for q-row quad*4+r of group g
    const int b = bh >> 4, h = bh & 15;
#pragma unroll
    for (int g = 0; g < 2; ++g) {
        float linv[4];
#pragma unroll
        for (int r = 0; r < 4; ++r) linv[r] = 1.0f / lacc[g][r];
#pragma unroll
        for (int nb = 0; nb < 4; ++nb)
#pragma unroll
            for (int r = 0; r < 4; ++r) {
                int n = qt * 128 + wave * 32 + g * 16 + quad * 4 + r;
                int cc = nb * 16 + l16;
                AOb[((size_t)b * SEQ + n) * EMB + h * CHD + cc] = f2bf(O[g][nb][r] * linv[r]);
            }
    }
}

// ---------------- output projection ----------------
__global__ __launch_bounds__(256) void out_gemm(const short* __restrict__ AOb,
                                                const short* __restrict__ Wob,
                                                const float* __restrict__ bo,
                                                float* __restrict__ out) {
    __shared__ short As[2 * 4096], Bs[2 * 4096];
    const int bm = blockIdx.x, bn = blockIdx.y;

    f32x4 acc[4][4];
    const f32x4 z = {0.f, 0.f, 0.f, 0.f};
#pragma unroll
    for (int i = 0; i < 4; ++i)
#pragma unroll
        for (int j = 0; j < 4; ++j) acc[i][j] = z;

    gemm_core(AOb + (size_t)bm * 128 * KDIM, Wob + (size_t)bn * 128 * KDIM, As, Bs, acc);

    const int lane = threadIdx.x & 63, wave = threadIdx.x >> 6;
    const int quad = lane >> 4, l16 = lane & 15;
    const int wm = (wave >> 1) * 64, wn = (wave & 1) * 64;
#pragma unroll
    for (int i = 0; i < 4; ++i)
#pragma unroll
        for (int j = 0; j < 4; ++j)
#pragma unroll
            for (int r = 0; r < 4; ++r) {
                int token = bm * 128 + wm + i * 16 + quad * 4 + r;
                int e = bn * 128 + wn + j * 16 + l16;
                out[(size_t)token * EMB + e] = acc[i][j][r] + bo[e];
            }
}

// ---------------- launch ----------------
extern "C" void kernel_launch(void* const* d_in, const int* in_sizes, int n_in,
                              void* d_out, int out_size, void* d_ws, size_t ws_size,
                              hipStream_t stream) {
    const float* x  = (const float*)d_in[0];
    const float* Wq = (const float*)d_in[1];
    const float* bq = (const float*)d_in[2];
    const float* Wk = (const float*)d_in[3];
    const float* bk = (const float*)d_in[4];
    const float* Wv = (const float*)d_in[5];
    const float* bv = (const float*)d_in[6];
    const float* Wo = (const float*)d_in[7];
    const float* bo = (const float*)d_in[8];

    char* ws = (char*)d_ws;
    short* xb  = (short*)(ws + 0);                         // 16 MB
    short* Wqb = (short*)(ws + (size_t)16 * 1024 * 1024);  // 2 MB (Q rows 0-1023)
    short* Wkb = (short*)(ws + (size_t)18 * 1024 * 1024);  // 2 MB (K rows, contiguous after Q)
    short* Wvb = (short*)(ws + (size_t)20 * 1024 * 1024);
    short* Wob = (short*)(ws + (size_t)22 * 1024 * 1024);
    short* Qb  = (short*)(ws + (size_t)24 * 1024 * 1024);  // 16 MB
    short* Kb  = (short*)(ws + (size_t)40 * 1024 * 1024);  // 16 MB
    short* Vtb = (short*)(ws + (size_t)56 * 1024 * 1024);  // 16 MB
    short* AOb = (short*)(ws + (size_t)72 * 1024 * 1024);  // 16 MB

    static bool s_cfg = false;
    if (!s_cfg) {
        hipFuncSetAttribute(reinterpret_cast<const void*>(qk256),
                            hipFuncAttributeMaxDynamicSharedMemorySize, 131072);
        s_cfg = true;
    }

    cvt_all<<<dim3(8192 + 4096), dim3(256), 0, stream>>>(x, Wq, Wk, Wv, Wo,
                                                         xb, Wqb, Wkb, Wvb, Wob);
    qk256<<<dim3(32, 8), dim3(512), 131072, stream>>>(xb, Wqb, bq, bk, Qb, Kb);
    vproj<<<dim3(64, 8), dim3(256), 0, stream>>>(xb, Wvb, bv, Vtb);
    attn<<<dim3(1024), dim3(256), 0, stream>>>(Qb, Kb, Vtb, AOb);
    out_gemm<<<dim3(64, 8), dim3(256), 0, stream>>>(AOb, Wob, bo, (float*)d_out);
}